// Round 3
// baseline (338.083 us; speedup 1.0000x reference)
//
#include <hip/hip_runtime.h>

// Haar 3D wavelet transform, x:(2,3,33,512,512) f32 -> out:(2,24,17,256,256) f32.
// channel = f*3 + c, f bit layout: f = ft*4 + fh*2 + fw, sign = (-1)^(ft*t+fh*h+fw*w).
// Memory-bound pure stream: ~208 MB read + ~214 MB write, zero reuse.
// This rev: (1) defer ALL stores to the end, grouped filter-major so each filter
// plane's two 512B halves (q=0,q=1) issue back-to-back -> single 1KB DRAM burst
// per plane per wave instead of two temporally-separated 512B bursts (nt stores
// are evict-first, so separated halves can't merge in L2).
// (2) pre-scale inputs by HAAR_SCALE: fewer muls, shorter load->store dep chain.

#define HAAR_SCALE 0.3536f

typedef float f4 __attribute__((ext_vector_type(4)));
typedef float f2 __attribute__((ext_vector_type(2)));

__global__ __launch_bounds__(256) void haar3d_kernel(const float* __restrict__ x,
                                                     float* __restrict__ out) {
    const int lane = threadIdx.x & 63;           // 0..63
    const int wv   = threadIdx.x >> 6;           // wave 0..3
    const int h    = (blockIdx.x << 2) + wv;     // output row 0..255 (one per wave)
    const int t    = blockIdx.y;                 // 0..16 output frame
    const int bc   = blockIdx.z;                 // 0..5 (b*3 + c)
    const int b    = bc / 3;
    const int c    = bc - b * 3;

    // causal replicate pad: padded frames (2t, 2t+1) = orig frames (max(2t-1,0), 2t)
    const int fr0 = max(2 * t - 1, 0);
    const int fr1 = 2 * t;

    const long long in_plane = (long long)bc * 33LL * 512LL * 512LL;
    const float* r00 = x + in_plane + ((long long)fr0 * 512 + 2 * h) * 512;  // t0, row 2h
    const float* r01 = r00 + 512;                                            // t0, row 2h+1
    const float* r10 = x + in_plane + ((long long)fr1 * 512 + 2 * h) * 512;  // t1, row 2h
    const float* r11 = r10 + 512;                                            // t1, row 2h+1

    // 8 dense float4 loads: half q covers input cols [256q, 256q+256);
    // lane l gets input cols 256q + 4l .. +3 of all 4 rows. Every 128B line is
    // requested exactly once by exactly one instruction.
    f4 v00[2], v01[2], v10[2], v11[2];
#pragma unroll
    for (int q = 0; q < 2; ++q) {
        const int off = 256 * q + 4 * lane;
        v00[q] = __builtin_nontemporal_load((const f4*)(r00 + off));
        v01[q] = __builtin_nontemporal_load((const f4*)(r01 + off));
        v10[q] = __builtin_nontemporal_load((const f4*)(r10 + off));
        v11[q] = __builtin_nontemporal_load((const f4*)(r11 + off));
    }

    // res[q][f]: lane's output cols {128q + 2l, 128q + 2l + 1} of filter f
    f2 res[2][8];
#pragma unroll
    for (int q = 0; q < 2; ++q) {
#pragma unroll
        for (int j = 0; j < 2; ++j) {
            // pre-scaled inputs (x*s): butterflies become pure add/sub
            const float v000 = v00[q][2 * j] * HAAR_SCALE, v001 = v00[q][2 * j + 1] * HAAR_SCALE;
            const float v010 = v01[q][2 * j] * HAAR_SCALE, v011 = v01[q][2 * j + 1] * HAAR_SCALE;
            const float v100 = v10[q][2 * j] * HAAR_SCALE, v101 = v10[q][2 * j + 1] * HAAR_SCALE;
            const float v110 = v11[q][2 * j] * HAAR_SCALE, v111 = v11[q][2 * j + 1] * HAAR_SCALE;
            // stage 1: w butterfly
            const float pw00 = v000 + v001, mw00 = v000 - v001;
            const float pw01 = v010 + v011, mw01 = v010 - v011;
            const float pw10 = v100 + v101, mw10 = v100 - v101;
            const float pw11 = v110 + v111, mw11 = v110 - v111;
            // stage 2: h butterfly
            const float pp0 = pw00 + pw01, pm0 = pw00 - pw01;
            const float mp0 = mw00 + mw01, mm0 = mw00 - mw01;
            const float pp1 = pw10 + pw11, pm1 = pw10 - pw11;
            const float mp1 = mw10 + mw11, mm1 = mw10 - mw11;
            // stage 3: t butterfly; f = ft*4 + fh*2 + fw
            res[q][0][j] = pp0 + pp1;  // 000
            res[q][1][j] = mp0 + mp1;  // 001 w-flip
            res[q][2][j] = pm0 + pm1;  // 010 h-flip
            res[q][3][j] = mm0 + mm1;  // 011
            res[q][4][j] = pp0 - pp1;  // 100 t-flip
            res[q][5][j] = mp0 - mp1;  // 101
            res[q][6][j] = pm0 - pm1;  // 110
            res[q][7][j] = mm0 - mm1;  // 111
        }
    }

    // out index: ((b*24 + f*3 + c)*17 + t)*256*256 + h*256 + col
    // All 16 stores issued back-to-back, filter-major: per plane the q=0 (cols
    // 2l) and q=1 (cols 128+2l) 512B chunks are adjacent in issue order.
    const long long fstride = 3LL * 17LL * 256LL * 256LL;
    float* obase = out + (((long long)(b * 24 + c) * 17 + t) * 256LL + h) * 256LL + 2 * lane;
#pragma unroll
    for (int f = 0; f < 8; ++f) {
        float* dst = obase + (long long)f * fstride;
        __builtin_nontemporal_store(res[0][f], (f2*)dst);
        __builtin_nontemporal_store(res[1][f], (f2*)(dst + 128));
    }
}

extern "C" void kernel_launch(void* const* d_in, const int* in_sizes, int n_in,
                              void* d_out, int out_size, void* d_ws, size_t ws_size,
                              hipStream_t stream) {
    const float* x = (const float*)d_in[0];
    float* out = (float*)d_out;
    dim3 grid(64, 17, 6);   // 64 row-groups (4 rows each), 17 frames, 6 (b,c) planes
    dim3 block(256);
    haar3d_kernel<<<grid, block, 0, stream>>>(x, out);
}